// Round 1
// baseline (931.935 us; speedup 1.0000x reference)
//
#include <hip/hip_runtime.h>

#define N_NODES 50000
#define N_REL   3
#define N_EDGE  200000
// dims: DIN=128, DHID=128, DOUT=64 (K is always 128)

// ---------------- degree count + norm ----------------
__global__ __launch_bounds__(256) void deg_count_kernel(
    const int* __restrict__ src, const int* __restrict__ dst,
    float* __restrict__ odeg, float* __restrict__ ideg)
{
    int i = blockIdx.x * 256 + threadIdx.x;
    if (i >= N_REL * N_EDGE) return;
    int r = i / N_EDGE;
    unsafeAtomicAdd(&odeg[r * N_NODES + src[i]], 1.0f);
    unsafeAtomicAdd(&ideg[r * N_NODES + dst[i]], 1.0f);
}

__global__ __launch_bounds__(256) void norm_kernel(
    float* __restrict__ odeg, float* __restrict__ ideg)
{
    int i = blockIdx.x * 256 + threadIdx.x;
    if (i >= N_REL * N_NODES) return;
    odeg[i] = rsqrtf(fmaxf(odeg[i], 1.0f));
    ideg[i] = rsqrtf(fmaxf(ideg[i], 1.0f));
}

// ---------------- bias broadcast init: buf[n,d] = sum_r b[r,d] ----------------
__global__ __launch_bounds__(256) void init_bias_kernel(
    float* __restrict__ buf, const float* __restrict__ b, int total, int dmask)
{
    int i = blockIdx.x * 256 + threadIdx.x;
    if (i >= total) return;
    int j = i & dmask;          // d is a power of two (128 or 64)
    int d = dmask + 1;
    buf[i] = b[j] + b[d + j] + b[2 * d + j];
}

// ---------------- tiled fp32 GEMM: Y[nrows,ldw] = act(A[nrows,128]) @ W[128,ldw] tile ----------------
// 64x64 output tile per block, 256 threads, K staged in two 64-chunks.
// As stored transposed [k][m] with +1 pad so compute reads are ds_read_b128.
template <bool RELU_IN>
__global__ __launch_bounds__(256) void gemm_k128(
    const float* __restrict__ A, const float* __restrict__ W,
    float* __restrict__ Y, int nrows, int ldw)
{
    __shared__ float As[64][65];   // [k][m], padded: store 2-way (free), read broadcast
    __shared__ float Bs[64][64];   // [k][n], read is 16 distinct b128 -> 2/bank (free)

    const int tid   = threadIdx.x;
    const int mt    = blockIdx.x * 64;
    const int nt    = blockIdx.y * 64;
    const int tx    = tid & 15;    // output col group
    const int ty    = tid >> 4;    // output row group (0..15)
    const int lcol4 = tid & 15;    // loader: float4 index within 64-wide k-slab
    const int lrow  = tid >> 4;    // loader: row within pass

    float acc[4][4] = {};

    for (int kk = 0; kk < 128; kk += 64) {
        #pragma unroll
        for (int p = 0; p < 4; ++p) {
            // A tile: 64 rows x 64 k's
            int row = lrow + p * 16;
            int gr  = mt + row;
            float4 v = make_float4(0.f, 0.f, 0.f, 0.f);
            if (gr < nrows)
                v = *reinterpret_cast<const float4*>(&A[(size_t)gr * 128 + kk + lcol4 * 4]);
            if (RELU_IN) {
                v.x = fmaxf(v.x, 0.f); v.y = fmaxf(v.y, 0.f);
                v.z = fmaxf(v.z, 0.f); v.w = fmaxf(v.w, 0.f);
            }
            As[lcol4 * 4 + 0][row] = v.x;
            As[lcol4 * 4 + 1][row] = v.y;
            As[lcol4 * 4 + 2][row] = v.z;
            As[lcol4 * 4 + 3][row] = v.w;
            // B tile: 64 k's x 64 cols (row-major, same layout as global)
            int kr = lrow + p * 16;
            float4 w = *reinterpret_cast<const float4*>(&W[(size_t)(kk + kr) * ldw + nt + lcol4 * 4]);
            *reinterpret_cast<float4*>(&Bs[kr][lcol4 * 4]) = w;
        }
        __syncthreads();

        #pragma unroll 8
        for (int k = 0; k < 64; ++k) {
            float4 a4 = *reinterpret_cast<const float4*>(&As[k][ty * 4]);
            float4 b4 = *reinterpret_cast<const float4*>(&Bs[k][tx * 4]);
            float av[4] = {a4.x, a4.y, a4.z, a4.w};
            float bv[4] = {b4.x, b4.y, b4.z, b4.w};
            #pragma unroll
            for (int i = 0; i < 4; ++i)
                #pragma unroll
                for (int j = 0; j < 4; ++j)
                    acc[i][j] = fmaf(av[i], bv[j], acc[i][j]);
        }
        __syncthreads();
    }

    #pragma unroll
    for (int i = 0; i < 4; ++i) {
        int gr = mt + ty * 4 + i;
        if (gr < nrows) {
            float4 o = make_float4(acc[i][0], acc[i][1], acc[i][2], acc[i][3]);
            *reinterpret_cast<float4*>(&Y[(size_t)gr * ldw + nt + tx * 4]) = o;
        }
    }
}

// ---------------- edge scatter: out[dst] += c * Y[src], c = onorm[src]*inorm[dst] ----------------
// One wave per edge. D=128: lane handles float2. D=64: lane handles one float.
__global__ __launch_bounds__(256) void scatter128_kernel(
    const float* __restrict__ Y, const int* __restrict__ src, const int* __restrict__ dst,
    const float* __restrict__ onorm, const float* __restrict__ inorm,
    float* __restrict__ out, int nedges)
{
    int wid  = (blockIdx.x * 256 + threadIdx.x) >> 6;
    int lane = threadIdx.x & 63;
    if (wid >= nedges) return;
    int s = src[wid], t = dst[wid];
    float c = onorm[s] * inorm[t];
    float2 y = *reinterpret_cast<const float2*>(&Y[(size_t)s * 128 + lane * 2]);
    unsafeAtomicAdd(&out[(size_t)t * 128 + lane * 2 + 0], c * y.x);
    unsafeAtomicAdd(&out[(size_t)t * 128 + lane * 2 + 1], c * y.y);
}

__global__ __launch_bounds__(256) void scatter64_kernel(
    const float* __restrict__ Y, const int* __restrict__ src, const int* __restrict__ dst,
    const float* __restrict__ onorm, const float* __restrict__ inorm,
    float* __restrict__ out, int nedges)
{
    int wid  = (blockIdx.x * 256 + threadIdx.x) >> 6;
    int lane = threadIdx.x & 63;
    if (wid >= nedges) return;
    int s = src[wid], t = dst[wid];
    float c = onorm[s] * inorm[t];
    float y = Y[(size_t)s * 64 + lane];
    unsafeAtomicAdd(&out[(size_t)t * 64 + lane], c * y);
}

extern "C" void kernel_launch(void* const* d_in, const int* in_sizes, int n_in,
                              void* d_out, int out_size, void* d_ws, size_t ws_size,
                              hipStream_t stream)
{
    const float* x   = (const float*)d_in[0];   // [N,128]
    const float* W1  = (const float*)d_in[1];   // [3,128,128]
    const float* b1  = (const float*)d_in[2];   // [3,128]
    const float* W2  = (const float*)d_in[3];   // [3,128,64]
    const float* b2  = (const float*)d_in[4];   // [3,64]
    const int*   src = (const int*)d_in[5];     // [3,E]
    const int*   dst = (const int*)d_in[6];     // [3,E]
    float*       out = (float*)d_out;           // [N,64]

    // workspace layout (floats): onorm[R*N] | inorm[R*N] | h[N*128] | Ybuf[N*128]
    float* ws    = (float*)d_ws;
    float* onorm = ws;
    float* inorm = onorm + (size_t)N_REL * N_NODES;
    float* h     = inorm + (size_t)N_REL * N_NODES;
    float* Ybuf  = h + (size_t)N_NODES * 128;

    // 1) degrees -> norms (graph identical for both layers; compute once)
    hipMemsetAsync(onorm, 0, (size_t)2 * N_REL * N_NODES * sizeof(float), stream);
    deg_count_kernel<<<(N_REL * N_EDGE + 255) / 256, 256, 0, stream>>>(src, dst, onorm, inorm);
    norm_kernel<<<(N_REL * N_NODES + 255) / 256, 256, 0, stream>>>(onorm, inorm);

    const int mtiles = (N_NODES + 63) / 64;
    const int scat_blocks = (N_EDGE + 3) / 4;   // 4 waves (edges) per block

    // 2) layer 1: h = b1sum; for r: Y = x @ W1_r; h[dst] += c*Y[src]
    init_bias_kernel<<<(N_NODES * 128 + 255) / 256, 256, 0, stream>>>(h, b1, N_NODES * 128, 127);
    for (int r = 0; r < N_REL; ++r) {
        gemm_k128<false><<<dim3(mtiles, 2), 256, 0, stream>>>(
            x, W1 + (size_t)r * 128 * 128, Ybuf, N_NODES, 128);
        scatter128_kernel<<<scat_blocks, 256, 0, stream>>>(
            Ybuf, src + (size_t)r * N_EDGE, dst + (size_t)r * N_EDGE,
            onorm + (size_t)r * N_NODES, inorm + (size_t)r * N_NODES, h, N_EDGE);
    }

    // 3) layer 2: out = b2sum; for r: Y = relu(h) @ W2_r; out[dst] += c*Y[src]
    init_bias_kernel<<<(N_NODES * 64 + 255) / 256, 256, 0, stream>>>(out, b2, N_NODES * 64, 63);
    for (int r = 0; r < N_REL; ++r) {
        gemm_k128<true><<<dim3(mtiles, 1), 256, 0, stream>>>(
            h, W2 + (size_t)r * 128 * 64, Ybuf, N_NODES, 64);
        scatter64_kernel<<<scat_blocks, 256, 0, stream>>>(
            Ybuf, src + (size_t)r * N_EDGE, dst + (size_t)r * N_EDGE,
            onorm + (size_t)r * N_NODES, inorm + (size_t)r * N_NODES, out, N_EDGE);
    }
}

// Round 2
// 432.131 us; speedup vs baseline: 2.1566x; 2.1566x over previous
//
#include <hip/hip_runtime.h>

#define N_NODES 50000
#define N_REL   3
#define N_EDGE  200000
#define RN      (N_REL * N_NODES)      // 150000 bins (relation, dst-node)
#define RE      (N_REL * N_EDGE)       // 600000 edges total
// dims: DIN=128, DHID=128, DOUT=64 (GEMM K is always 128)

// ---------------- degree count ----------------
__global__ __launch_bounds__(256) void deg_count_kernel(
    const int* __restrict__ src, const int* __restrict__ dst,
    float* __restrict__ odeg, float* __restrict__ ideg)
{
    int i = blockIdx.x * 256 + threadIdx.x;
    if (i >= RE) return;
    int r = i / N_EDGE;
    unsafeAtomicAdd(&odeg[r * N_NODES + src[i]], 1.0f);
    unsafeAtomicAdd(&ideg[r * N_NODES + dst[i]], 1.0f);
}

__global__ __launch_bounds__(256) void norm_kernel(
    float* __restrict__ odeg, float* __restrict__ ideg)
{
    int i = blockIdx.x * 256 + threadIdx.x;
    if (i >= RN) return;
    odeg[i] = rsqrtf(fmaxf(odeg[i], 1.0f));
    ideg[i] = rsqrtf(fmaxf(ideg[i], 1.0f));
}

// ---------------- hierarchical exclusive scan over RN in-degree counts ----------------
// scan1: 147 blocks x 1024 elems -> local-exclusive offsets + per-block sums
__global__ __launch_bounds__(256) void scan1_kernel(
    const float* __restrict__ ideg, int* __restrict__ off, int* __restrict__ bsums)
{
    __shared__ int tsum[256];
    int tid  = threadIdx.x;
    int base = blockIdx.x * 1024 + tid * 4;
    int c[4], s = 0;
    #pragma unroll
    for (int j = 0; j < 4; ++j) {
        c[j] = (base + j < RN) ? (int)ideg[base + j] : 0;
        s += c[j];
    }
    tsum[tid] = s;
    __syncthreads();
    #pragma unroll
    for (int d = 1; d < 256; d <<= 1) {
        int v   = tsum[tid];
        int add = (tid >= d) ? tsum[tid - d] : 0;
        __syncthreads();
        tsum[tid] = v + add;
        __syncthreads();
    }
    int run = tsum[tid] - s;   // exclusive within block
    #pragma unroll
    for (int j = 0; j < 4; ++j) {
        if (base + j < RN) off[base + j] = run;
        run += c[j];
    }
    if (tid == 255) bsums[blockIdx.x] = tsum[255];
}

// scan2: exclusive scan of <=256 block sums, single block
__global__ __launch_bounds__(256) void scan2_kernel(int* __restrict__ bsums, int nb)
{
    __shared__ int t[256];
    int tid = threadIdx.x;
    int v0  = (tid < nb) ? bsums[tid] : 0;
    t[tid] = v0;
    __syncthreads();
    #pragma unroll
    for (int d = 1; d < 256; d <<= 1) {
        int v   = t[tid];
        int add = (tid >= d) ? t[tid - d] : 0;
        __syncthreads();
        t[tid] = v + add;
        __syncthreads();
    }
    if (tid < nb) bsums[tid] = t[tid] - v0;  // exclusive
}

// scan3: add block offset; materialize cursor copy; terminator
__global__ __launch_bounds__(256) void scan3_kernel(
    int* __restrict__ off, int* __restrict__ cursor, const int* __restrict__ bsums)
{
    int tid  = threadIdx.x;
    int base = blockIdx.x * 1024 + tid * 4;
    int add  = bsums[blockIdx.x];
    #pragma unroll
    for (int j = 0; j < 4; ++j) {
        if (base + j < RN) {
            int v = off[base + j] + add;
            off[base + j]    = v;
            cursor[base + j] = v;
        }
    }
    if (blockIdx.x == 0 && tid == 0) off[RN] = RE;
}

// ---------------- CSR fill: payload packs (src, onorm[r][src]) ----------------
__global__ __launch_bounds__(256) void fill_kernel(
    const int* __restrict__ src, const int* __restrict__ dst,
    const float* __restrict__ onorm, int* __restrict__ cursor, int2* __restrict__ csr)
{
    int i = blockIdx.x * 256 + threadIdx.x;
    if (i >= N_EDGE) return;
    int r = blockIdx.y;
    int s = src[r * N_EDGE + i];
    int t = dst[r * N_EDGE + i];
    int bin = r * N_NODES + t;
    float w = onorm[r * N_NODES + s];
    int pos = atomicAdd(&cursor[bin], 1);
    csr[pos] = make_int2(s, __float_as_int(w));
}

// ---------------- f32 -> bf16 (round-to-nearest-even) ----------------
__device__ __forceinline__ unsigned short f2bf(float f) {
    unsigned u = __float_as_uint(f);
    u = (u + 0x7fffu + ((u >> 16) & 1u)) >> 16;
    return (unsigned short)u;
}

// ---------------- tiled fp32 GEMM: Ybf[z][nrows,ldw] = act(A[nrows,128]) @ W[z][128,ldw] ----------------
// 64x64 tile / 256 threads; A transposed in LDS (+1 pad); bf16 output.
template <bool RELU_IN>
__global__ __launch_bounds__(256) void gemm_k128(
    const float* __restrict__ A, const float* __restrict__ Wbase,
    unsigned short* __restrict__ Ybase, int nrows, int ldw)
{
    __shared__ float As[64][65];
    __shared__ float Bs[64][64];

    const float* W = Wbase + (size_t)blockIdx.z * 128 * ldw;
    unsigned short* Y = Ybase + (size_t)blockIdx.z * N_NODES * ldw;

    const int tid   = threadIdx.x;
    const int mt    = blockIdx.x * 64;
    const int nt    = blockIdx.y * 64;
    const int tx    = tid & 15;
    const int ty    = tid >> 4;
    const int lcol4 = tid & 15;
    const int lrow  = tid >> 4;

    float acc[4][4] = {};

    for (int kk = 0; kk < 128; kk += 64) {
        #pragma unroll
        for (int p = 0; p < 4; ++p) {
            int row = lrow + p * 16;
            int gr  = mt + row;
            float4 v = make_float4(0.f, 0.f, 0.f, 0.f);
            if (gr < nrows)
                v = *reinterpret_cast<const float4*>(&A[(size_t)gr * 128 + kk + lcol4 * 4]);
            if (RELU_IN) {
                v.x = fmaxf(v.x, 0.f); v.y = fmaxf(v.y, 0.f);
                v.z = fmaxf(v.z, 0.f); v.w = fmaxf(v.w, 0.f);
            }
            As[lcol4 * 4 + 0][row] = v.x;
            As[lcol4 * 4 + 1][row] = v.y;
            As[lcol4 * 4 + 2][row] = v.z;
            As[lcol4 * 4 + 3][row] = v.w;
            int kr = lrow + p * 16;
            float4 w = *reinterpret_cast<const float4*>(&W[(size_t)(kk + kr) * ldw + nt + lcol4 * 4]);
            *reinterpret_cast<float4*>(&Bs[kr][lcol4 * 4]) = w;
        }
        __syncthreads();

        #pragma unroll 8
        for (int k = 0; k < 64; ++k) {
            float4 a4 = *reinterpret_cast<const float4*>(&As[k][ty * 4]);
            float4 b4 = *reinterpret_cast<const float4*>(&Bs[k][tx * 4]);
            float av[4] = {a4.x, a4.y, a4.z, a4.w};
            float bv[4] = {b4.x, b4.y, b4.z, b4.w};
            #pragma unroll
            for (int i = 0; i < 4; ++i)
                #pragma unroll
                for (int j = 0; j < 4; ++j)
                    acc[i][j] = fmaf(av[i], bv[j], acc[i][j]);
        }
        __syncthreads();
    }

    #pragma unroll
    for (int i = 0; i < 4; ++i) {
        int gr = mt + ty * 4 + i;
        if (gr < nrows) {
            ushort4 o;
            o.x = f2bf(acc[i][0]); o.y = f2bf(acc[i][1]);
            o.z = f2bf(acc[i][2]); o.w = f2bf(acc[i][3]);
            *reinterpret_cast<ushort4*>(&Y[(size_t)gr * ldw + nt + tx * 4]) = o;
        }
    }
}

// ---------------- gather aggregation, layer 1 (D=128) ----------------
// One wave per dst node; all 3 relations; lane holds 2 dims (bf16x2 = 4B gather/lane).
__global__ __launch_bounds__(256) void agg128_kernel(
    const unsigned* __restrict__ Y, const int2* __restrict__ csr,
    const int* __restrict__ off, const float* __restrict__ inorm,
    const float* __restrict__ b, float* __restrict__ h)
{
    int wid  = (blockIdx.x * 256 + threadIdx.x) >> 6;
    int lane = threadIdx.x & 63;
    if (wid >= N_NODES) return;

    float a0 = 0.f, a1 = 0.f;
    #pragma unroll
    for (int r = 0; r < N_REL; ++r) {
        int bin = r * N_NODES + wid;
        int beg = off[bin], end = off[bin + 1];
        float rn = inorm[bin];
        float s0 = 0.f, s1 = 0.f;
        for (int e = beg; e < end; ++e) {
            int2 p  = csr[e];
            float w = __int_as_float(p.y);
            unsigned y = Y[(r * N_NODES + p.x) * 64 + lane];
            float y0 = __uint_as_float(y << 16);
            float y1 = __uint_as_float(y & 0xffff0000u);
            s0 = fmaf(w, y0, s0);
            s1 = fmaf(w, y1, s1);
        }
        a0 = fmaf(rn, s0, a0);
        a1 = fmaf(rn, s1, a1);
    }
    int d = lane * 2;
    float bs0 = b[d]     + b[128 + d]     + b[256 + d];
    float bs1 = b[d + 1] + b[128 + d + 1] + b[256 + d + 1];
    float2 o = make_float2(a0 + bs0, a1 + bs1);
    *reinterpret_cast<float2*>(&h[(size_t)wid * 128 + d]) = o;
}

// ---------------- gather aggregation, layer 2 (D=64) ----------------
__global__ __launch_bounds__(256) void agg64_kernel(
    const unsigned short* __restrict__ Y, const int2* __restrict__ csr,
    const int* __restrict__ off, const float* __restrict__ inorm,
    const float* __restrict__ b, float* __restrict__ out)
{
    int wid  = (blockIdx.x * 256 + threadIdx.x) >> 6;
    int lane = threadIdx.x & 63;
    if (wid >= N_NODES) return;

    float a = 0.f;
    #pragma unroll
    for (int r = 0; r < N_REL; ++r) {
        int bin = r * N_NODES + wid;
        int beg = off[bin], end = off[bin + 1];
        float rn = inorm[bin];
        float s = 0.f;
        for (int e = beg; e < end; ++e) {
            int2 p  = csr[e];
            float w = __int_as_float(p.y);
            unsigned short yu = Y[(r * N_NODES + p.x) * 64 + lane];
            float y = __uint_as_float(((unsigned)yu) << 16);
            s = fmaf(w, y, s);
        }
        a = fmaf(rn, s, a);
    }
    float bs = b[lane] + b[64 + lane] + b[128 + lane];
    out[(size_t)wid * 64 + lane] = a + bs;
}

extern "C" void kernel_launch(void* const* d_in, const int* in_sizes, int n_in,
                              void* d_out, int out_size, void* d_ws, size_t ws_size,
                              hipStream_t stream)
{
    const float* x   = (const float*)d_in[0];   // [N,128]
    const float* W1  = (const float*)d_in[1];   // [3,128,128]
    const float* b1  = (const float*)d_in[2];   // [3,128]
    const float* W2  = (const float*)d_in[3];   // [3,128,64]
    const float* b2  = (const float*)d_in[4];   // [3,64]
    const int*   src = (const int*)d_in[5];     // [3,E]
    const int*   dst = (const int*)d_in[6];     // [3,E]
    float*       out = (float*)d_out;           // [N,64]

    // workspace layout
    char* w = (char*)d_ws;
    float* onorm  = (float*)w;                 w += (size_t)RN * 4;
    float* inorm  = (float*)w;                 w += (size_t)RN * 4;
    int*   off    = (int*)w;                   w += (size_t)(RN + 1) * 4;
    int*   cursor = (int*)w;                   w += (size_t)RN * 4;
    int*   bsums  = (int*)w;                   w += 1024;
    int2*  csr    = (int2*)w;                  w += (size_t)RE * 8;
    float* h      = (float*)w;                 w += (size_t)N_NODES * 128 * 4;
    unsigned short* Ybf = (unsigned short*)w;  // 3*N*128*2 = 38.4MB (reused for layer 2)

    const int SCAN_BLOCKS = (RN + 1023) / 1024;   // 147
    const int mtiles = (N_NODES + 63) / 64;       // 782

    // 1) degrees
    hipMemsetAsync(onorm, 0, (size_t)2 * RN * 4, stream);
    deg_count_kernel<<<(RE + 255) / 256, 256, 0, stream>>>(src, dst, onorm, inorm);

    // 2) CSR offsets from in-degree counts (before norm overwrites them)
    scan1_kernel<<<SCAN_BLOCKS, 256, 0, stream>>>(inorm, off, bsums);
    scan2_kernel<<<1, 256, 0, stream>>>(bsums, SCAN_BLOCKS);
    scan3_kernel<<<SCAN_BLOCKS, 256, 0, stream>>>(off, cursor, bsums);

    // 3) norms, then CSR fill (payload needs onorm)
    norm_kernel<<<(RN + 255) / 256, 256, 0, stream>>>(onorm, inorm);
    fill_kernel<<<dim3((N_EDGE + 255) / 256, N_REL), 256, 0, stream>>>(src, dst, onorm, cursor, csr);

    // 4) layer 1: Y_r = x @ W1_r (bf16 out), then gather-aggregate into h
    gemm_k128<false><<<dim3(mtiles, 2, N_REL), 256, 0, stream>>>(x, W1, Ybf, N_NODES, 128);
    agg128_kernel<<<(N_NODES + 3) / 4, 256, 0, stream>>>((const unsigned*)Ybf, csr, off, inorm, b1, h);

    // 5) layer 2: Y_r = relu(h) @ W2_r (bf16 out), gather-aggregate into out
    gemm_k128<true><<<dim3(mtiles, 1, N_REL), 256, 0, stream>>>(h, W2, Ybf, N_NODES, 64);
    agg64_kernel<<<(N_NODES + 3) / 4, 256, 0, stream>>>(Ybf, csr, off, inorm, b2, out);
}

// Round 3
// 405.065 us; speedup vs baseline: 2.3007x; 1.0668x over previous
//
#include <hip/hip_runtime.h>

#define N_NODES 50000
#define N_REL   3
#define N_EDGE  200000
#define RN      (N_REL * N_NODES)      // 150000 bins (relation, dst-node)
#define RE      (N_REL * N_EDGE)       // 600000 edges total
// dims: DIN=128, DHID=128, DOUT=64 (GEMM K is always 128)

typedef short bf16x8 __attribute__((ext_vector_type(8)));
typedef float f32x4  __attribute__((ext_vector_type(4)));

// ---------------- degree count ----------------
__global__ __launch_bounds__(256) void deg_count_kernel(
    const int* __restrict__ src, const int* __restrict__ dst,
    float* __restrict__ odeg, float* __restrict__ ideg)
{
    int i = blockIdx.x * 256 + threadIdx.x;
    if (i >= RE) return;
    int r = i / N_EDGE;
    unsafeAtomicAdd(&odeg[r * N_NODES + src[i]], 1.0f);
    unsafeAtomicAdd(&ideg[r * N_NODES + dst[i]], 1.0f);
}

__global__ __launch_bounds__(256) void norm_kernel(
    float* __restrict__ odeg, float* __restrict__ ideg)
{
    int i = blockIdx.x * 256 + threadIdx.x;
    if (i >= RN) return;
    odeg[i] = rsqrtf(fmaxf(odeg[i], 1.0f));
    ideg[i] = rsqrtf(fmaxf(ideg[i], 1.0f));
}

// ---------------- hierarchical exclusive scan over RN in-degree counts ----------------
__global__ __launch_bounds__(256) void scan1_kernel(
    const float* __restrict__ ideg, int* __restrict__ off, int* __restrict__ bsums)
{
    __shared__ int tsum[256];
    int tid  = threadIdx.x;
    int base = blockIdx.x * 1024 + tid * 4;
    int c[4], s = 0;
    #pragma unroll
    for (int j = 0; j < 4; ++j) {
        c[j] = (base + j < RN) ? (int)ideg[base + j] : 0;
        s += c[j];
    }
    tsum[tid] = s;
    __syncthreads();
    #pragma unroll
    for (int d = 1; d < 256; d <<= 1) {
        int v   = tsum[tid];
        int add = (tid >= d) ? tsum[tid - d] : 0;
        __syncthreads();
        tsum[tid] = v + add;
        __syncthreads();
    }
    int run = tsum[tid] - s;
    #pragma unroll
    for (int j = 0; j < 4; ++j) {
        if (base + j < RN) off[base + j] = run;
        run += c[j];
    }
    if (tid == 255) bsums[blockIdx.x] = tsum[255];
}

__global__ __launch_bounds__(256) void scan2_kernel(int* __restrict__ bsums, int nb)
{
    __shared__ int t[256];
    int tid = threadIdx.x;
    int v0  = (tid < nb) ? bsums[tid] : 0;
    t[tid] = v0;
    __syncthreads();
    #pragma unroll
    for (int d = 1; d < 256; d <<= 1) {
        int v   = t[tid];
        int add = (tid >= d) ? t[tid - d] : 0;
        __syncthreads();
        t[tid] = v + add;
        __syncthreads();
    }
    if (tid < nb) bsums[tid] = t[tid] - v0;
}

__global__ __launch_bounds__(256) void scan3_kernel(
    int* __restrict__ off, int* __restrict__ cursor, const int* __restrict__ bsums)
{
    int tid  = threadIdx.x;
    int base = blockIdx.x * 1024 + tid * 4;
    int add  = bsums[blockIdx.x];
    #pragma unroll
    for (int j = 0; j < 4; ++j) {
        if (base + j < RN) {
            int v = off[base + j] + add;
            off[base + j]    = v;
            cursor[base + j] = v;
        }
    }
    if (blockIdx.x == 0 && tid == 0) off[RN] = RE;
}

// ---------------- CSR fill: payload packs (src, onorm[r][src]) ----------------
__global__ __launch_bounds__(256) void fill_kernel(
    const int* __restrict__ src, const int* __restrict__ dst,
    const float* __restrict__ onorm, int* __restrict__ cursor, int2* __restrict__ csr)
{
    int i = blockIdx.x * 256 + threadIdx.x;
    if (i >= N_EDGE) return;
    int r = blockIdx.y;
    int s = src[r * N_EDGE + i];
    int t = dst[r * N_EDGE + i];
    int bin = r * N_NODES + t;
    float w = onorm[r * N_NODES + s];
    int pos = atomicAdd(&cursor[bin], 1);
    csr[pos] = make_int2(s, __float_as_int(w));
}

// ---------------- f32 -> bf16 (RNE) ----------------
__device__ __forceinline__ unsigned short f2bf(float f) {
    unsigned u = __float_as_uint(f);
    u = (u + 0x7fffu + ((u >> 16) & 1u)) >> 16;
    return (unsigned short)u;
}
__device__ __forceinline__ unsigned pack_bf2(float lo, float hi) {
    return (unsigned)f2bf(lo) | ((unsigned)f2bf(hi) << 16);
}

// ---------------- W transpose+convert: Wt[rel][n][k] = bf16(W[rel][k][n]) ----------------
__global__ __launch_bounds__(256) void wtrans_kernel(
    const float* __restrict__ W, unsigned short* __restrict__ Wt,
    int ncols, int total)   // K=128 fixed; total = 3*128*ncols
{
    int i = blockIdx.x * 256 + threadIdx.x;
    if (i >= total) return;
    int rel = i / (128 * ncols);
    int rem = i - rel * 128 * ncols;
    int k   = rem / ncols;
    int n   = rem - k * ncols;
    Wt[((size_t)(rel * ncols + n)) * 128 + k] = f2bf(W[i]);
}

// ---------------- MFMA GEMM: Y[rel][row][0:NCOLS] = act(A[row,0:128]) @ W[rel] ----------------
// 64-row strip / block, 4 waves. A staged once in LDS (bf16, stride-68 words),
// a-frags in regs reused across all (rel, ntile) passes. B-frags streamed from
// pre-transposed bf16 Wt in global (L2-resident). D layout: col=lane&15,
// row=(lane>>4)*4+reg (m89-verified). A/B share the same k-indexing, so the
// result is independent of the exact per-lane k permutation.
template <bool RELU, int NCOLS>
__global__ __launch_bounds__(256) void gemm_mfma(
    const float* __restrict__ A, const unsigned short* __restrict__ Wt,
    unsigned short* __restrict__ Y, int nrows)
{
    __shared__ unsigned As[64 * 68];   // word = 2 bf16; row stride 68 words

    const int tid = threadIdx.x;
    const int mt  = blockIdx.x * 64;

    // stage A tile: 64 rows x 128 k (4096 words)
    #pragma unroll
    for (int p = 0; p < 16; ++p) {
        int q   = tid + p * 256;
        int row = q >> 6, wc = q & 63;
        int gr  = mt + row;
        float2 v = make_float2(0.f, 0.f);
        if (gr < nrows) v = *reinterpret_cast<const float2*>(&A[(size_t)gr * 128 + wc * 2]);
        if (RELU) { v.x = fmaxf(v.x, 0.f); v.y = fmaxf(v.y, 0.f); }
        As[row * 68 + wc] = pack_bf2(v.x, v.y);
    }
    __syncthreads();

    const int w  = tid >> 6;        // wave id: rows w*16..w*16+15
    const int l  = tid & 63;
    const int g  = l >> 4;          // k-group
    const int ar = w * 16 + (l & 15);

    bf16x8 a[4];
    #pragma unroll
    for (int kb = 0; kb < 4; ++kb)
        a[kb] = *reinterpret_cast<const bf16x8*>(&As[ar * 68 + kb * 16 + g * 4]);

    const int NPASS = 3 * (NCOLS / 64);
    #pragma unroll
    for (int pass = 0; pass < NPASS; ++pass) {
        int rel = (NCOLS == 128) ? (pass >> 1) : pass;
        int nt  = (NCOLS == 128) ? ((pass & 1) * 64) : 0;

        f32x4 acc[4];
        #pragma unroll
        for (int cf = 0; cf < 4; ++cf) {
            acc[cf] = (f32x4){0.f, 0.f, 0.f, 0.f};
            int col = nt + cf * 16 + (l & 15);
            const unsigned short* wp = &Wt[((size_t)(rel * NCOLS + col)) * 128 + g * 8];
            #pragma unroll
            for (int kb = 0; kb < 4; ++kb) {
                bf16x8 b = *reinterpret_cast<const bf16x8*>(wp + kb * 32);
                acc[cf] = __builtin_amdgcn_mfma_f32_16x16x32_bf16(a[kb], b, acc[cf], 0, 0, 0);
            }
        }

        #pragma unroll
        for (int cf = 0; cf < 4; ++cf) {
            #pragma unroll
            for (int i = 0; i < 4; ++i) {
                int grow = mt + w * 16 + g * 4 + i;
                if (grow < nrows)
                    Y[((size_t)rel * N_NODES + grow) * NCOLS + nt + cf * 16 + (l & 15)] =
                        f2bf(acc[cf][i]);
            }
        }
    }
}

// ---------------- gather aggregation, layer 1 (D=128) ----------------
__global__ __launch_bounds__(256) void agg128_kernel(
    const unsigned* __restrict__ Y, const int2* __restrict__ csr,
    const int* __restrict__ off, const float* __restrict__ inorm,
    const float* __restrict__ b, float* __restrict__ h)
{
    int wid  = (blockIdx.x * 256 + threadIdx.x) >> 6;
    int lane = threadIdx.x & 63;
    if (wid >= N_NODES) return;

    float a0 = 0.f, a1 = 0.f;
    #pragma unroll
    for (int r = 0; r < N_REL; ++r) {
        int bin = r * N_NODES + wid;
        int beg = off[bin], end = off[bin + 1];
        float rn = inorm[bin];
        float s0 = 0.f, s1 = 0.f;
        for (int e = beg; e < end; ++e) {
            int2 p  = csr[e];
            float w = __int_as_float(p.y);
            unsigned y = Y[(r * N_NODES + p.x) * 64 + lane];
            float y0 = __uint_as_float(y << 16);
            float y1 = __uint_as_float(y & 0xffff0000u);
            s0 = fmaf(w, y0, s0);
            s1 = fmaf(w, y1, s1);
        }
        a0 = fmaf(rn, s0, a0);
        a1 = fmaf(rn, s1, a1);
    }
    int d = lane * 2;
    float bs0 = b[d]     + b[128 + d]     + b[256 + d];
    float bs1 = b[d + 1] + b[128 + d + 1] + b[256 + d + 1];
    float2 o = make_float2(a0 + bs0, a1 + bs1);
    *reinterpret_cast<float2*>(&h[(size_t)wid * 128 + d]) = o;
}

// ---------------- gather aggregation, layer 2 (D=64) ----------------
__global__ __launch_bounds__(256) void agg64_kernel(
    const unsigned short* __restrict__ Y, const int2* __restrict__ csr,
    const int* __restrict__ off, const float* __restrict__ inorm,
    const float* __restrict__ b, float* __restrict__ out)
{
    int wid  = (blockIdx.x * 256 + threadIdx.x) >> 6;
    int lane = threadIdx.x & 63;
    if (wid >= N_NODES) return;

    float a = 0.f;
    #pragma unroll
    for (int r = 0; r < N_REL; ++r) {
        int bin = r * N_NODES + wid;
        int beg = off[bin], end = off[bin + 1];
        float rn = inorm[bin];
        float s = 0.f;
        for (int e = beg; e < end; ++e) {
            int2 p  = csr[e];
            float w = __int_as_float(p.y);
            unsigned short yu = Y[(r * N_NODES + p.x) * 64 + lane];
            float y = __uint_as_float(((unsigned)yu) << 16);
            s = fmaf(w, y, s);
        }
        a = fmaf(rn, s, a);
    }
    float bs = b[lane] + b[64 + lane] + b[128 + lane];
    out[(size_t)wid * 64 + lane] = a + bs;
}

extern "C" void kernel_launch(void* const* d_in, const int* in_sizes, int n_in,
                              void* d_out, int out_size, void* d_ws, size_t ws_size,
                              hipStream_t stream)
{
    const float* x   = (const float*)d_in[0];   // [N,128]
    const float* W1  = (const float*)d_in[1];   // [3,128,128]
    const float* b1  = (const float*)d_in[2];   // [3,128]
    const float* W2  = (const float*)d_in[3];   // [3,128,64]
    const float* b2  = (const float*)d_in[4];   // [3,64]
    const int*   src = (const int*)d_in[5];     // [3,E]
    const int*   dst = (const int*)d_in[6];     // [3,E]
    float*       out = (float*)d_out;           // [N,64]

    // workspace layout (16B-aligned chunks)
    char* w = (char*)d_ws;
    float* onorm  = (float*)w;                 w += (size_t)RN * 4;
    float* inorm  = (float*)w;                 w += (size_t)RN * 4;
    int*   off    = (int*)w;                   w += (size_t)(RN + 1) * 4;
    int*   cursor = (int*)w;                   w += (size_t)RN * 4;
    int*   bsums  = (int*)w;                   w += 1024;
    w = (char*)(((uintptr_t)w + 255) & ~(uintptr_t)255);
    int2*  csr    = (int2*)w;                  w += (size_t)RE * 8;
    float* h      = (float*)w;                 w += (size_t)N_NODES * 128 * 4;
    unsigned short* Ybf = (unsigned short*)w;  w += (size_t)N_REL * N_NODES * 128 * 2;
    unsigned short* Wt1 = (unsigned short*)w;  w += (size_t)N_REL * 128 * 128 * 2;
    unsigned short* Wt2 = (unsigned short*)w;  // 3*64*128*2

    const int SCAN_BLOCKS = (RN + 1023) / 1024;   // 147
    const int mtiles = (N_NODES + 63) / 64;       // 782

    // 0) weight transpose+convert (tiny)
    wtrans_kernel<<<(3 * 128 * 128 + 255) / 256, 256, 0, stream>>>(W1, Wt1, 128, 3 * 128 * 128);
    wtrans_kernel<<<(3 * 128 * 64 + 255) / 256, 256, 0, stream>>>(W2, Wt2, 64, 3 * 128 * 64);

    // 1) degrees
    hipMemsetAsync(onorm, 0, (size_t)2 * RN * 4, stream);
    deg_count_kernel<<<(RE + 255) / 256, 256, 0, stream>>>(src, dst, onorm, inorm);

    // 2) CSR offsets from in-degree counts (before norm overwrites them)
    scan1_kernel<<<SCAN_BLOCKS, 256, 0, stream>>>(inorm, off, bsums);
    scan2_kernel<<<1, 256, 0, stream>>>(bsums, SCAN_BLOCKS);
    scan3_kernel<<<SCAN_BLOCKS, 256, 0, stream>>>(off, cursor, bsums);

    // 3) norms, then CSR fill
    norm_kernel<<<(RN + 255) / 256, 256, 0, stream>>>(onorm, inorm);
    fill_kernel<<<dim3((N_EDGE + 255) / 256, N_REL), 256, 0, stream>>>(src, dst, onorm, cursor, csr);

    // 4) layer 1: Y_r = x @ W1_r (bf16, MFMA), then gather-aggregate into h
    gemm_mfma<false, 128><<<mtiles, 256, 0, stream>>>(x, Wt1, Ybf, N_NODES);
    agg128_kernel<<<(N_NODES + 3) / 4, 256, 0, stream>>>((const unsigned*)Ybf, csr, off, inorm, b1, h);

    // 5) layer 2: Y_r = relu(h) @ W2_r (bf16, MFMA), gather-aggregate into out
    gemm_mfma<true, 64><<<mtiles, 256, 0, stream>>>(h, Wt2, Ybf, N_NODES);
    agg64_kernel<<<(N_NODES + 3) / 4, 256, 0, stream>>>(Ybf, csr, off, inorm, b2, out);
}

// Round 4
// 330.921 us; speedup vs baseline: 2.8162x; 1.2241x over previous
//
#include <hip/hip_runtime.h>

#define N_NODES 50000
#define N_REL   3
#define N_EDGE  200000
#define RN      (N_REL * N_NODES)      // 150000 (relation, node) pairs for norms
#define RE      (N_REL * N_EDGE)       // 600000 edges total
// dims: DIN=128, DHID=128, DOUT=64 (GEMM K is always 128)

typedef short bf16x8 __attribute__((ext_vector_type(8)));
typedef float f32x4  __attribute__((ext_vector_type(4)));

// ---------------- degree count ----------------
__global__ __launch_bounds__(256) void deg_count_kernel(
    const int* __restrict__ src, const int* __restrict__ dst,
    float* __restrict__ odeg, float* __restrict__ ideg)
{
    int i = blockIdx.x * 256 + threadIdx.x;
    if (i >= RE) return;
    int r = i / N_EDGE;
    unsafeAtomicAdd(&odeg[r * N_NODES + src[i]], 1.0f);
    unsafeAtomicAdd(&ideg[r * N_NODES + dst[i]], 1.0f);
}

__global__ __launch_bounds__(256) void norm_kernel(
    float* __restrict__ odeg, float* __restrict__ ideg)
{
    int i = blockIdx.x * 256 + threadIdx.x;
    if (i >= RN) return;
    odeg[i] = rsqrtf(fmaxf(odeg[i], 1.0f));
    ideg[i] = rsqrtf(fmaxf(ideg[i], 1.0f));
}

// ---------------- exclusive scan over N_NODES combined in-degree (sum of 3 rels) ----------------
__global__ __launch_bounds__(256) void scan1_kernel(
    const float* __restrict__ ideg, int* __restrict__ off, int* __restrict__ bsums)
{
    __shared__ int tsum[256];
    int tid  = threadIdx.x;
    int base = blockIdx.x * 1024 + tid * 4;
    int c[4], s = 0;
    #pragma unroll
    for (int j = 0; j < 4; ++j) {
        int idx = base + j;
        c[j] = (idx < N_NODES)
             ? (int)(ideg[idx] + ideg[N_NODES + idx] + ideg[2 * N_NODES + idx]) : 0;
        s += c[j];
    }
    tsum[tid] = s;
    __syncthreads();
    #pragma unroll
    for (int d = 1; d < 256; d <<= 1) {
        int v   = tsum[tid];
        int add = (tid >= d) ? tsum[tid - d] : 0;
        __syncthreads();
        tsum[tid] = v + add;
        __syncthreads();
    }
    int run = tsum[tid] - s;
    #pragma unroll
    for (int j = 0; j < 4; ++j) {
        if (base + j < N_NODES) off[base + j] = run;
        run += c[j];
    }
    if (tid == 255) bsums[blockIdx.x] = tsum[255];
}

__global__ __launch_bounds__(256) void scan2_kernel(int* __restrict__ bsums, int nb)
{
    __shared__ int t[256];
    int tid = threadIdx.x;
    int v0  = (tid < nb) ? bsums[tid] : 0;
    t[tid] = v0;
    __syncthreads();
    #pragma unroll
    for (int d = 1; d < 256; d <<= 1) {
        int v   = t[tid];
        int add = (tid >= d) ? t[tid - d] : 0;
        __syncthreads();
        t[tid] = v + add;
        __syncthreads();
    }
    if (tid < nb) bsums[tid] = t[tid] - v0;
}

__global__ __launch_bounds__(256) void scan3_kernel(
    int* __restrict__ off, int* __restrict__ cursor, const int* __restrict__ bsums)
{
    int tid  = threadIdx.x;
    int base = blockIdx.x * 1024 + tid * 4;
    int add  = bsums[blockIdx.x];
    #pragma unroll
    for (int j = 0; j < 4; ++j) {
        if (base + j < N_NODES) {
            int v = off[base + j] + add;
            off[base + j]    = v;
            cursor[base + j] = v;
        }
    }
    if (blockIdx.x == 0 && tid == 0) off[N_NODES] = RE;
}

// ---------------- CSR fill: bin by dst; payload = (r*N+src, onorm[r][src]*inorm[r][dst]) ----------------
__global__ __launch_bounds__(256) void fill_kernel(
    const int* __restrict__ src, const int* __restrict__ dst,
    const float* __restrict__ onorm, const float* __restrict__ inorm,
    int* __restrict__ cursor, int2* __restrict__ csr)
{
    int i = blockIdx.x * 256 + threadIdx.x;
    if (i >= N_EDGE) return;
    int r = blockIdx.y;
    int s = src[r * N_EDGE + i];
    int t = dst[r * N_EDGE + i];
    float wv = onorm[r * N_NODES + s] * inorm[r * N_NODES + t];
    int pos = atomicAdd(&cursor[t], 1);
    csr[pos] = make_int2(r * N_NODES + s, __float_as_int(wv));
}

// ---------------- f32 -> bf16 (RNE) ----------------
__device__ __forceinline__ unsigned short f2bf(float f) {
    unsigned u = __float_as_uint(f);
    u = (u + 0x7fffu + ((u >> 16) & 1u)) >> 16;
    return (unsigned short)u;
}
__device__ __forceinline__ unsigned pack_bf2(float lo, float hi) {
    return (unsigned)f2bf(lo) | ((unsigned)f2bf(hi) << 16);
}

// ---------------- W transpose+convert: Wt[rel][n][k] = bf16(W[rel][k][n]) ----------------
__global__ __launch_bounds__(256) void wtrans_kernel(
    const float* __restrict__ W, unsigned short* __restrict__ Wt,
    int ncols, int total)
{
    int i = blockIdx.x * 256 + threadIdx.x;
    if (i >= total) return;
    int rel = i / (128 * ncols);
    int rem = i - rel * 128 * ncols;
    int k   = rem / ncols;
    int n   = rem - k * ncols;
    Wt[((size_t)(rel * ncols + n)) * 128 + k] = f2bf(W[i]);
}

// ---------------- MFMA GEMM: Y[rel][row][0:NCOLS] = act(A[row,0:128]) @ W[rel] ----------------
template <bool RELU, int NCOLS>
__global__ __launch_bounds__(256) void gemm_mfma(
    const float* __restrict__ A, const unsigned short* __restrict__ Wt,
    unsigned short* __restrict__ Y, int nrows)
{
    __shared__ unsigned As[64 * 68];   // word = 2 bf16; row stride 68 words

    const int tid = threadIdx.x;
    const int mt  = blockIdx.x * 64;

    #pragma unroll
    for (int p = 0; p < 16; ++p) {
        int q   = tid + p * 256;
        int row = q >> 6, wc = q & 63;
        int gr  = mt + row;
        float2 v = make_float2(0.f, 0.f);
        if (gr < nrows) v = *reinterpret_cast<const float2*>(&A[(size_t)gr * 128 + wc * 2]);
        if (RELU) { v.x = fmaxf(v.x, 0.f); v.y = fmaxf(v.y, 0.f); }
        As[row * 68 + wc] = pack_bf2(v.x, v.y);
    }
    __syncthreads();

    const int w  = tid >> 6;
    const int l  = tid & 63;
    const int g  = l >> 4;
    const int ar = w * 16 + (l & 15);

    bf16x8 a[4];
    #pragma unroll
    for (int kb = 0; kb < 4; ++kb)
        a[kb] = *reinterpret_cast<const bf16x8*>(&As[ar * 68 + kb * 16 + g * 4]);

    const int NPASS = 3 * (NCOLS / 64);
    #pragma unroll
    for (int pass = 0; pass < NPASS; ++pass) {
        int rel = (NCOLS == 128) ? (pass >> 1) : pass;
        int nt  = (NCOLS == 128) ? ((pass & 1) * 64) : 0;

        f32x4 acc[4];
        #pragma unroll
        for (int cf = 0; cf < 4; ++cf) {
            acc[cf] = (f32x4){0.f, 0.f, 0.f, 0.f};
            int col = nt + cf * 16 + (l & 15);
            const unsigned short* wp = &Wt[((size_t)(rel * NCOLS + col)) * 128 + g * 8];
            #pragma unroll
            for (int kb = 0; kb < 4; ++kb) {
                bf16x8 b = *reinterpret_cast<const bf16x8*>(wp + kb * 32);
                acc[cf] = __builtin_amdgcn_mfma_f32_16x16x32_bf16(a[kb], b, acc[cf], 0, 0, 0);
            }
        }

        #pragma unroll
        for (int cf = 0; cf < 4; ++cf) {
            #pragma unroll
            for (int i = 0; i < 4; ++i) {
                int grow = mt + w * 16 + g * 4 + i;
                if (grow < nrows)
                    Y[((size_t)rel * N_NODES + grow) * NCOLS + nt + cf * 16 + (l & 15)] =
                        f2bf(acc[cf][i]);
            }
        }
    }
}

// ---------------- gather aggregation, layer 1 (D=128), fused CSR, unroll-8 ----------------
// One wave per dst node; lane holds 2 dims (4B gather/lane); weights pre-scaled.
__global__ __launch_bounds__(256) void agg128_kernel(
    const unsigned* __restrict__ Y, const int2* __restrict__ csr,
    const int* __restrict__ off, const float* __restrict__ b, float* __restrict__ h)
{
    int wid  = (blockIdx.x * 256 + threadIdx.x) >> 6;
    int lane = threadIdx.x & 63;
    if (wid >= N_NODES) return;

    int e = off[wid], end = off[wid + 1];
    float a0 = 0.f, a1 = 0.f;

    for (; e + 8 <= end; e += 8) {
        int2 p[8]; unsigned y[8];
        #pragma unroll
        for (int j = 0; j < 8; ++j) p[j] = csr[e + j];
        #pragma unroll
        for (int j = 0; j < 8; ++j) y[j] = Y[(size_t)p[j].x * 64 + lane];
        #pragma unroll
        for (int j = 0; j < 8; ++j) {
            float wv = __int_as_float(p[j].y);
            a0 = fmaf(wv, __uint_as_float(y[j] << 16), a0);
            a1 = fmaf(wv, __uint_as_float(y[j] & 0xffff0000u), a1);
        }
    }
    if (e + 4 <= end) {
        int2 p[4]; unsigned y[4];
        #pragma unroll
        for (int j = 0; j < 4; ++j) p[j] = csr[e + j];
        #pragma unroll
        for (int j = 0; j < 4; ++j) y[j] = Y[(size_t)p[j].x * 64 + lane];
        #pragma unroll
        for (int j = 0; j < 4; ++j) {
            float wv = __int_as_float(p[j].y);
            a0 = fmaf(wv, __uint_as_float(y[j] << 16), a0);
            a1 = fmaf(wv, __uint_as_float(y[j] & 0xffff0000u), a1);
        }
        e += 4;
    }
    for (; e < end; ++e) {
        int2 p = csr[e];
        float wv = __int_as_float(p.y);
        unsigned y = Y[(size_t)p.x * 64 + lane];
        a0 = fmaf(wv, __uint_as_float(y << 16), a0);
        a1 = fmaf(wv, __uint_as_float(y & 0xffff0000u), a1);
    }

    int d = lane * 2;
    float bs0 = b[d]     + b[128 + d]     + b[256 + d];
    float bs1 = b[d + 1] + b[128 + d + 1] + b[256 + d + 1];
    *reinterpret_cast<float2*>(&h[(size_t)wid * 128 + d]) =
        make_float2(a0 + bs0, a1 + bs1);
}

// ---------------- gather aggregation, layer 2 (D=64), fused CSR, unroll-8 ----------------
__global__ __launch_bounds__(256) void agg64_kernel(
    const unsigned short* __restrict__ Y, const int2* __restrict__ csr,
    const int* __restrict__ off, const float* __restrict__ b, float* __restrict__ out)
{
    int wid  = (blockIdx.x * 256 + threadIdx.x) >> 6;
    int lane = threadIdx.x & 63;
    if (wid >= N_NODES) return;

    int e = off[wid], end = off[wid + 1];
    float a = 0.f;

    for (; e + 8 <= end; e += 8) {
        int2 p[8]; unsigned short y[8];
        #pragma unroll
        for (int j = 0; j < 8; ++j) p[j] = csr[e + j];
        #pragma unroll
        for (int j = 0; j < 8; ++j) y[j] = Y[(size_t)p[j].x * 64 + lane];
        #pragma unroll
        for (int j = 0; j < 8; ++j)
            a = fmaf(__int_as_float(p[j].y),
                     __uint_as_float(((unsigned)y[j]) << 16), a);
    }
    if (e + 4 <= end) {
        int2 p[4]; unsigned short y[4];
        #pragma unroll
        for (int j = 0; j < 4; ++j) p[j] = csr[e + j];
        #pragma unroll
        for (int j = 0; j < 4; ++j) y[j] = Y[(size_t)p[j].x * 64 + lane];
        #pragma unroll
        for (int j = 0; j < 4; ++j)
            a = fmaf(__int_as_float(p[j].y),
                     __uint_as_float(((unsigned)y[j]) << 16), a);
        e += 4;
    }
    for (; e < end; ++e) {
        int2 p = csr[e];
        a = fmaf(__int_as_float(p.y),
                 __uint_as_float(((unsigned)Y[(size_t)p.x * 64 + lane]) << 16), a);
    }

    float bs = b[lane] + b[64 + lane] + b[128 + lane];
    out[(size_t)wid * 64 + lane] = a + bs;
}

extern "C" void kernel_launch(void* const* d_in, const int* in_sizes, int n_in,
                              void* d_out, int out_size, void* d_ws, size_t ws_size,
                              hipStream_t stream)
{
    const float* x   = (const float*)d_in[0];   // [N,128]
    const float* W1  = (const float*)d_in[1];   // [3,128,128]
    const float* b1  = (const float*)d_in[2];   // [3,128]
    const float* W2  = (const float*)d_in[3];   // [3,128,64]
    const float* b2  = (const float*)d_in[4];   // [3,64]
    const int*   src = (const int*)d_in[5];     // [3,E]
    const int*   dst = (const int*)d_in[6];     // [3,E]
    float*       out = (float*)d_out;           // [N,64]

    // workspace layout
    char* w = (char*)d_ws;
    float* onorm  = (float*)w;                 w += (size_t)RN * 4;
    float* inorm  = (float*)w;                 w += (size_t)RN * 4;
    int*   off    = (int*)w;                   w += (size_t)(N_NODES + 1) * 4;
    int*   cursor = (int*)w;                   w += (size_t)N_NODES * 4;
    int*   bsums  = (int*)w;                   w += 1024;
    w = (char*)(((uintptr_t)w + 255) & ~(uintptr_t)255);
    int2*  csr    = (int2*)w;                  w += (size_t)RE * 8;
    float* h      = (float*)w;                 w += (size_t)N_NODES * 128 * 4;
    unsigned short* Ybf = (unsigned short*)w;  w += (size_t)N_REL * N_NODES * 128 * 2;
    unsigned short* Wt1 = (unsigned short*)w;  w += (size_t)N_REL * 128 * 128 * 2;
    unsigned short* Wt2 = (unsigned short*)w;  // 3*64*128*2

    const int SCAN_BLOCKS = (N_NODES + 1023) / 1024;   // 49
    const int mtiles = (N_NODES + 63) / 64;            // 782

    // 0) weight transpose+convert (tiny)
    wtrans_kernel<<<(3 * 128 * 128 + 255) / 256, 256, 0, stream>>>(W1, Wt1, 128, 3 * 128 * 128);
    wtrans_kernel<<<(3 * 128 * 64 + 255) / 256, 256, 0, stream>>>(W2, Wt2, 64, 3 * 128 * 64);

    // 1) degrees
    hipMemsetAsync(onorm, 0, (size_t)2 * RN * 4, stream);
    deg_count_kernel<<<(RE + 255) / 256, 256, 0, stream>>>(src, dst, onorm, inorm);

    // 2) CSR offsets from combined in-degree (before norm overwrites counts)
    scan1_kernel<<<SCAN_BLOCKS, 256, 0, stream>>>(inorm, off, bsums);
    scan2_kernel<<<1, 256, 0, stream>>>(bsums, SCAN_BLOCKS);
    scan3_kernel<<<SCAN_BLOCKS, 256, 0, stream>>>(off, cursor, bsums);

    // 3) norms, then CSR fill (weight folds inorm*onorm; index folds relation)
    norm_kernel<<<(RN + 255) / 256, 256, 0, stream>>>(onorm, inorm);
    fill_kernel<<<dim3((N_EDGE + 255) / 256, N_REL), 256, 0, stream>>>(
        src, dst, onorm, inorm, cursor, csr);

    // 4) layer 1: Y_r = x @ W1_r (bf16, MFMA), then gather-aggregate into h
    gemm_mfma<false, 128><<<mtiles, 256, 0, stream>>>(x, Wt1, Ybf, N_NODES);
    agg128_kernel<<<(N_NODES + 3) / 4, 256, 0, stream>>>((const unsigned*)Ybf, csr, off, b1, h);

    // 5) layer 2: Y_r = relu(h) @ W2_r (bf16, MFMA), gather-aggregate into out
    gemm_mfma<true, 64><<<mtiles, 256, 0, stream>>>(h, Wt2, Ybf, N_NODES);
    agg64_kernel<<<(N_NODES + 3) / 4, 256, 0, stream>>>(Ybf, csr, off, b2, out);
}